// Round 5
// baseline (408.915 us; speedup 1.0000x reference)
//
#include <hip/hip_runtime.h>
#include <hip/hip_bf16.h>

#define N_GRAPHS 64

// ---------------------------------------------------------------------------
__global__ void k_deg(const int* __restrict__ dst, int E, int* __restrict__ deg) {
    int i = blockIdx.x * blockDim.x + threadIdx.x;
    if (i < E) atomicAdd(&deg[dst[i]], 1);
}

// dis/xp + per-block deg sums (fused)
__global__ void k_dis_bsum(const int* __restrict__ deg, const float* __restrict__ x,
                           float* __restrict__ dis, float* __restrict__ xp,
                           int* __restrict__ bsum, int N) {
    int i = blockIdx.x * 256 + threadIdx.x;
    int dv = (i < N) ? deg[i] : 0;
    if (i < N) {
        float d = rsqrtf((float)(dv + 1));
        dis[i] = d;
        xp[i]  = d * x[i];
    }
    int v = dv;
#pragma unroll
    for (int o = 1; o < 64; o <<= 1) v += __shfl_xor(v, o);
    __shared__ int ws4[4];
    if ((threadIdx.x & 63) == 0) ws4[threadIdx.x >> 6] = v;
    __syncthreads();
    if (threadIdx.x == 0) bsum[blockIdx.x] = ws4[0] + ws4[1] + ws4[2] + ws4[3];
}

__device__ inline int block_scan_inc(int v, int* wsum) {
    int lane = threadIdx.x & 63, w = threadIdx.x >> 6;
    int iv = v;
#pragma unroll
    for (int o = 1; o < 64; o <<= 1) {
        int t = __shfl_up(iv, o);
        if (lane >= o) iv += t;
    }
    if (lane == 63) wsum[w] = iv;
    __syncthreads();
    int add = 0;
    for (int k = 0; k < w; ++k) add += wsum[k];
    return iv + add;
}

__global__ void k_scan_sums(const int* __restrict__ bsum, int nb, int* __restrict__ boff) {
    __shared__ int wsum[4];
    int tid = threadIdx.x;
    int v = (tid < nb) ? bsum[tid] : 0;
    int inc = block_scan_inc(v, wsum);
    if (tid < nb) boff[tid] = inc - v;   // exclusive
}

__global__ void k_scan_apply(const int* __restrict__ deg, const int* __restrict__ boff,
                             int* __restrict__ row_ptr, int N) {
    __shared__ int wsum[4];
    int b = blockIdx.x, i = b * 256 + threadIdx.x;
    int v = (i < N) ? deg[i] : 0;
    int inc = block_scan_inc(v, wsum) + boff[b];
    if (i < N) {
        row_ptr[i] = inc - v;
        if (i == N - 1) row_ptr[N] = inc;
    }
}

__global__ void k_scatter(const int* __restrict__ src, const int* __restrict__ dst, int E,
                          const int* __restrict__ row_ptr, int* __restrict__ fill,
                          int* __restrict__ csr_src) {
    int e = blockIdx.x * blockDim.x + threadIdx.x;
    if (e < E) {
        int d = dst[e];
        int pos = row_ptr[d] + atomicAdd(&fill[d], 1);
        csr_src[pos] = src[e];
    }
}

// t[d] = dis[d] * ( sum xp[s] + xp[d] )
__global__ void k_agg_scalar(const float* __restrict__ xp, const float* __restrict__ dis,
                             const int* __restrict__ row_ptr, const int* __restrict__ csr,
                             float* __restrict__ t, int N) {
    int d = blockIdx.x * blockDim.x + threadIdx.x;
    if (d >= N) return;
    float acc = xp[d];
    int e0 = row_ptr[d], e1 = row_ptr[d + 1];
    int e = e0;
    for (; e + 8 <= e1; e += 8) {
        int s0 = csr[e],     s1 = csr[e + 1], s2 = csr[e + 2], s3 = csr[e + 3];
        int s4 = csr[e + 4], s5 = csr[e + 5], s6 = csr[e + 6], s7 = csr[e + 7];
        acc += ((xp[s0] + xp[s1]) + (xp[s2] + xp[s3]))
             + ((xp[s4] + xp[s5]) + (xp[s6] + xp[s7]));
    }
    for (; e < e1; ++e) acc += xp[csr[e]];
    t[d] = dis[d] * acc;
}

// h1'[i][j] = dis[i] * relu(t[i]*W1[j] + b1[j])
__global__ void k_h1(const float* __restrict__ t, const float* __restrict__ dis,
                     const float* __restrict__ W1, const float* __restrict__ b1,
                     float* __restrict__ h1, int N) {
    __shared__ float w[128], bb[128];
    const int tid = threadIdx.x;
    if (tid < 128) { w[tid] = W1[tid]; bb[tid] = b1[tid]; }
    __syncthreads();
    int idx = blockIdx.x * 256 + tid;
    if (idx < N * 128) {
        int i = idx >> 7, j = idx & 127;
        float v = fmaf(t[i], w[j], bb[j]);
        h1[idx] = fmaxf(v, 0.f) * dis[i];
    }
}

// ---------------------------------------------------------------------------
// Fused {gather-aggregate -> LDS A-tile} + {tile GEMM}.
//   Phase 1: Al[nn][0..127] = dis[d] * (sum_{s in N(d)} Bin[s] + Bin[d]),
//            d = n0+nn  (Bin rows are pre-scaled by dis of the source node).
//   Phase 2: out[d][:] = relu(Al[d,:] @ W + b)  (* dis[d] if SCALE), or
//            FUSE_MAX: per-graph max -> atomicMax into gmax (no store).
// 256 threads, 64-node tile. W staged in 32-k chunks with register prefetch.
template<int FOUT, bool SCALE, bool FUSE_MAX, int MINW>
__global__ __launch_bounds__(256, MINW) void k_fused(
        const float4* __restrict__ Bin, const float* __restrict__ W,
        const float* __restrict__ b, const float* __restrict__ dis,
        const int* __restrict__ row_ptr, const int* __restrict__ csr,
        float* __restrict__ outp, const int* __restrict__ batch,
        unsigned int* __restrict__ gmax, int N) {
    constexpr int WROW = FOUT + 4;          // padded row words (132 / 260)
    constexpr int NPF  = (32 * FOUT) / (4 * 256);  // prefetch float4/thread (4 / 8)
    constexpr int JC   = FOUT / 4;          // float4 cols per W row
    constexpr int NC   = FOUT / 16;         // acc cols per thread (8 / 16)
    constexpr int NS   = FOUT / 64;         // 4-col col-groups (2 / 4)
    __shared__ float Al[64][132];
    __shared__ float Wl[32][WROW];
    const int tid = threadIdx.x;
    const int n0 = blockIdx.x * 64;

    // issue W chunk-0 loads now; they complete during the gather phase
    float4 wpf[NPF];
#pragma unroll
    for (int p = 0; p < NPF; ++p) {
        int idx = tid + p * 256;
        int kk = idx / JC, jc = idx % JC;
        wpf[p] = reinterpret_cast<const float4*>(W + (size_t)kk * FOUT)[jc];
    }

    // ---- phase 1: gather-aggregate into Al ----
    {
        const int sub = tid >> 5, lane = tid & 31;
        for (int r = 0; r < 8; ++r) {
            int nn = r * 8 + sub;
            int node = n0 + nn;
            float a0 = 0.f, a1 = 0.f, a2 = 0.f, a3 = 0.f;
            if (node < N) {
                float4 self = Bin[(size_t)node * 32 + lane];
                a0 = self.x; a1 = self.y; a2 = self.z; a3 = self.w;
                int e0 = row_ptr[node], e1 = row_ptr[node + 1];
                int e = e0;
                for (; e + 8 <= e1; e += 8) {
                    int s0 = csr[e],     s1 = csr[e + 1], s2 = csr[e + 2], s3 = csr[e + 3];
                    int s4 = csr[e + 4], s5 = csr[e + 5], s6 = csr[e + 6], s7 = csr[e + 7];
                    float4 v0 = Bin[(size_t)s0 * 32 + lane];
                    float4 v1 = Bin[(size_t)s1 * 32 + lane];
                    float4 v2 = Bin[(size_t)s2 * 32 + lane];
                    float4 v3 = Bin[(size_t)s3 * 32 + lane];
                    float4 v4 = Bin[(size_t)s4 * 32 + lane];
                    float4 v5 = Bin[(size_t)s5 * 32 + lane];
                    float4 v6 = Bin[(size_t)s6 * 32 + lane];
                    float4 v7 = Bin[(size_t)s7 * 32 + lane];
                    a0 += ((v0.x + v1.x) + (v2.x + v3.x)) + ((v4.x + v5.x) + (v6.x + v7.x));
                    a1 += ((v0.y + v1.y) + (v2.y + v3.y)) + ((v4.y + v5.y) + (v6.y + v7.y));
                    a2 += ((v0.z + v1.z) + (v2.z + v3.z)) + ((v4.z + v5.z) + (v6.z + v7.z));
                    a3 += ((v0.w + v1.w) + (v2.w + v3.w)) + ((v4.w + v5.w) + (v6.w + v7.w));
                }
                for (; e < e1; ++e) {
                    int s = csr[e];
                    float4 v = Bin[(size_t)s * 32 + lane];
                    a0 += v.x; a1 += v.y; a2 += v.z; a3 += v.w;
                }
                float d = dis[node];
                a0 *= d; a1 *= d; a2 *= d; a3 *= d;
            }
            *reinterpret_cast<float4*>(&Al[nn][lane * 4]) = make_float4(a0, a1, a2, a3);
        }
    }
    __syncthreads();

    // ---- phase 2: GEMM from LDS ----
    const int ng = tid >> 4;   // nodes ng + 16m
    const int cg = tid & 15;   // cols  cg*4 + 64s + r
    float acc[4][NC] = {};

    for (int kc = 0; kc < 128; kc += 32) {
        // commit prefetched W chunk to LDS
#pragma unroll
        for (int p = 0; p < NPF; ++p) {
            int idx = tid + p * 256;
            int kk = idx / JC, jc = idx % JC;
            *reinterpret_cast<float4*>(&Wl[kk][jc * 4]) = wpf[p];
        }
        __syncthreads();
        // issue next chunk's loads (hidden under compute)
        if (kc + 32 < 128) {
#pragma unroll
            for (int p = 0; p < NPF; ++p) {
                int idx = tid + p * 256;
                int kk = idx / JC, jc = idx % JC;
                wpf[p] = reinterpret_cast<const float4*>(
                    W + (size_t)(kc + 32 + kk) * FOUT)[jc];
            }
        }
#pragma unroll
        for (int k4 = 0; k4 < 8; ++k4) {
            float4 A0 = *reinterpret_cast<const float4*>(&Al[ng     ][kc + k4 * 4]);
            float4 A1 = *reinterpret_cast<const float4*>(&Al[ng + 16][kc + k4 * 4]);
            float4 A2 = *reinterpret_cast<const float4*>(&Al[ng + 32][kc + k4 * 4]);
            float4 A3 = *reinterpret_cast<const float4*>(&Al[ng + 48][kc + k4 * 4]);
            const float am[4][4] = {{A0.x,A0.y,A0.z,A0.w},{A1.x,A1.y,A1.z,A1.w},
                                    {A2.x,A2.y,A2.z,A2.w},{A3.x,A3.y,A3.z,A3.w}};
#pragma unroll
            for (int kk = 0; kk < 4; ++kk) {
                float wv[NC];
#pragma unroll
                for (int s = 0; s < NS; ++s) {
                    float4 w4 = *reinterpret_cast<const float4*>(
                        &Wl[k4 * 4 + kk][cg * 4 + 64 * s]);
                    wv[s * 4 + 0] = w4.x; wv[s * 4 + 1] = w4.y;
                    wv[s * 4 + 2] = w4.z; wv[s * 4 + 3] = w4.w;
                }
#pragma unroll
                for (int m = 0; m < 4; ++m)
#pragma unroll
                    for (int j = 0; j < NC; ++j)
                        acc[m][j] = fmaf(am[m][kk], wv[j], acc[m][j]);
            }
        }
        __syncthreads();
    }

    float bb[NC];
#pragma unroll
    for (int s = 0; s < NS; ++s)
#pragma unroll
        for (int r = 0; r < 4; ++r)
            bb[s * 4 + r] = b[cg * 4 + 64 * s + r];

    if (!FUSE_MAX) {
#pragma unroll
        for (int m = 0; m < 4; ++m) {
            int node = n0 + ng + 16 * m;
            if (node < N) {
                float dsc = SCALE ? dis[node] : 1.f;
                float* op = outp + (size_t)node * FOUT;
#pragma unroll
                for (int s = 0; s < NS; ++s) {
                    float o[4];
#pragma unroll
                    for (int r = 0; r < 4; ++r) {
                        float v = fmaxf(acc[m][s * 4 + r] + bb[s * 4 + r], 0.f);
                        o[r] = SCALE ? v * dsc : v;
                    }
                    *reinterpret_cast<float4*>(op + cg * 4 + 64 * s) =
                        make_float4(o[0], o[1], o[2], o[3]);
                }
            }
        }
    } else {
#pragma unroll
        for (int m = 0; m < 4; ++m)
#pragma unroll
            for (int j = 0; j < NC; ++j)
                acc[m][j] = fmaxf(acc[m][j] + bb[j], 0.f);
        int nbm[4];
#pragma unroll
        for (int m = 0; m < 4; ++m) {
            int node = n0 + ng + 16 * m;
            nbm[m] = (node < N) ? batch[node] : -1;
        }
        int gfirst = batch[n0];
        int glast  = batch[min(n0 + 63, N - 1)];
        for (int gb = gfirst; gb <= glast; ++gb) {
            float mx[NC];
#pragma unroll
            for (int j = 0; j < NC; ++j) mx[j] = 0.f;
#pragma unroll
            for (int m = 0; m < 4; ++m)
                if (nbm[m] == gb)
#pragma unroll
                    for (int j = 0; j < NC; ++j) mx[j] = fmaxf(mx[j], acc[m][j]);
            // reduce over ng within the wave (lane bits 4,5)
#pragma unroll
            for (int j = 0; j < NC; ++j) {
                mx[j] = fmaxf(mx[j], __shfl_xor(mx[j], 16));
                mx[j] = fmaxf(mx[j], __shfl_xor(mx[j], 32));
            }
            if ((tid & 48) == 0) {
#pragma unroll
                for (int s = 0; s < NS; ++s)
#pragma unroll
                    for (int r = 0; r < 4; ++r)
                        atomicMax(&gmax[gb * FOUT + cg * 4 + 64 * s + r],
                                  __float_as_uint(mx[s * 4 + r]));
            }
        }
    }
}

// final MLP: out = relu( relu(g@Wf1+bf1) @ Wf2 + bf2 )
__global__ void k_mlp(const float* __restrict__ g, const float* __restrict__ Wf1,
                      const float* __restrict__ bf1, const float* __restrict__ Wf2,
                      const float* __restrict__ bf2, float* __restrict__ out) {
    __shared__ float gr[256];
    __shared__ float g1s[128];
    const int gid = blockIdx.x;
    const int tid = threadIdx.x;
    gr[tid] = g[gid * 256 + tid];
    gr[tid + 128] = g[gid * 256 + 128 + tid];
    __syncthreads();
    float acc = bf1[tid];
    for (int k = 0; k < 256; ++k)
        acc = fmaf(gr[k], Wf1[k * 128 + tid], acc);
    g1s[tid] = fmaxf(acc, 0.f);
    __syncthreads();
    if (tid < 10) {
        float a = bf2[tid];
        for (int k = 0; k < 128; ++k)
            a = fmaf(g1s[k], Wf2[k * 10 + tid], a);
        out[gid * 10 + tid] = fmaxf(a, 0.f);
    }
}

// ---------------------------------------------------------------------------
extern "C" void kernel_launch(void* const* d_in, const int* in_sizes, int n_in,
                              void* d_out, int out_size, void* d_ws, size_t ws_size,
                              hipStream_t stream) {
    const float* x   = (const float*)d_in[0];
    const int*   ei  = (const int*)d_in[1];
    const int*   bat = (const int*)d_in[2];
    const float* W1  = (const float*)d_in[3];
    const float* b1  = (const float*)d_in[4];
    const float* W2  = (const float*)d_in[5];
    const float* b2  = (const float*)d_in[6];
    const float* W3  = (const float*)d_in[7];
    const float* b3  = (const float*)d_in[8];
    const float* Wf1 = (const float*)d_in[9];
    const float* bf1 = (const float*)d_in[10];
    const float* Wf2 = (const float*)d_in[11];
    const float* bf2 = (const float*)d_in[12];
    float* out = (float*)d_out;

    const int N = in_sizes[0];          // 50000
    const int E = in_sizes[1] / 2;      // 800000
    const int* src = ei;
    const int* dst = ei + E;

    char* base = (char*)d_ws;
    size_t off = 0;
    auto carve = [&](size_t bytes) -> char* {
        char* p = base + off;
        off = (off + bytes + 255) & ~(size_t)255;
        return p;
    };
    const int nb = (N + 255) / 256;
    int*   deg     = (int*)  carve((size_t)N * 4);
    int*   fill    = (int*)  carve((size_t)N * 4);
    int*   row_ptr = (int*)  carve((size_t)(N + 1) * 4);
    int*   csr     = (int*)  carve((size_t)E * 4);
    float* dis     = (float*)carve((size_t)N * 4);
    float* xp      = (float*)carve((size_t)N * 4);
    float* t       = (float*)carve((size_t)N * 4);
    float* B1      = (float*)carve((size_t)N * 128 * 4);
    float* B2      = (float*)carve((size_t)N * 128 * 4);
    unsigned int* g = (unsigned int*)carve((size_t)N_GRAPHS * 256 * 4);
    int*   bsum    = (int*)  carve((size_t)nb * 4);
    int*   boff    = (int*)  carve((size_t)nb * 4);
    (void)ws_size; (void)n_in; (void)out_size;

    hipMemsetAsync(deg, 0, (size_t)N * 4, stream);
    hipMemsetAsync(fill, 0, (size_t)N * 4, stream);
    hipMemsetAsync(g, 0, (size_t)N_GRAPHS * 256 * 4, stream);

    int eb = (E + 255) / 256;

    k_deg<<<eb, 256, 0, stream>>>(dst, E, deg);
    k_dis_bsum<<<nb, 256, 0, stream>>>(deg, x, dis, xp, bsum, N);
    k_scan_sums<<<1, 256, 0, stream>>>(bsum, nb, boff);
    k_scan_apply<<<nb, 256, 0, stream>>>(deg, boff, row_ptr, N);
    k_scatter<<<eb, 256, 0, stream>>>(src, dst, E, row_ptr, fill, csr);

    k_agg_scalar<<<nb, 256, 0, stream>>>(xp, dis, row_ptr, csr, t, N);
    k_h1<<<(N * 128 + 255) / 256, 256, 0, stream>>>(t, dis, W1, b1, B1, N);

    const int gx = (N + 63) / 64;
    // layer 2: gather(B1) -> GEMM W2 -> B2 (dis-scaled for next agg)
    k_fused<128, true, false, 3><<<gx, 256, 0, stream>>>(
        (const float4*)B1, W2, b2, dis, row_ptr, csr, B2, nullptr, nullptr, N);
    // layer 3: gather(B2) -> GEMM W3 -> fused per-graph max into g
    k_fused<256, false, true, 2><<<gx, 256, 0, stream>>>(
        (const float4*)B2, W3, b3, dis, row_ptr, csr, nullptr, bat, g, N);

    k_mlp<<<N_GRAPHS, 128, 0, stream>>>((const float*)g, Wf1, bf1, Wf2, bf2, out);
}

// Round 6
// 328.742 us; speedup vs baseline: 1.2439x; 1.2439x over previous
//
#include <hip/hip_runtime.h>
#include <hip/hip_bf16.h>

#define N_GRAPHS 64

// ---------------------------------------------------------------------------
__global__ void k_deg(const int* __restrict__ dst, int E, int* __restrict__ deg) {
    int i = blockIdx.x * blockDim.x + threadIdx.x;
    if (i < E) atomicAdd(&deg[dst[i]], 1);
}

// dis/xp + per-block deg sums (fused)
__global__ void k_dis_bsum(const int* __restrict__ deg, const float* __restrict__ x,
                           float* __restrict__ dis, float* __restrict__ xp,
                           int* __restrict__ bsum, int N) {
    int i = blockIdx.x * 256 + threadIdx.x;
    int dv = (i < N) ? deg[i] : 0;
    if (i < N) {
        float d = rsqrtf((float)(dv + 1));
        dis[i] = d;
        xp[i]  = d * x[i];
    }
    int v = dv;
#pragma unroll
    for (int o = 1; o < 64; o <<= 1) v += __shfl_xor(v, o);
    __shared__ int ws4[4];
    if ((threadIdx.x & 63) == 0) ws4[threadIdx.x >> 6] = v;
    __syncthreads();
    if (threadIdx.x == 0) bsum[blockIdx.x] = ws4[0] + ws4[1] + ws4[2] + ws4[3];
}

__device__ inline int block_scan_inc(int v, int* wsum) {
    int lane = threadIdx.x & 63, w = threadIdx.x >> 6;
    int iv = v;
#pragma unroll
    for (int o = 1; o < 64; o <<= 1) {
        int t = __shfl_up(iv, o);
        if (lane >= o) iv += t;
    }
    if (lane == 63) wsum[w] = iv;
    __syncthreads();
    int add = 0;
    for (int k = 0; k < w; ++k) add += wsum[k];
    return iv + add;
}

__global__ void k_scan_sums(const int* __restrict__ bsum, int nb, int* __restrict__ boff) {
    __shared__ int wsum[4];
    int tid = threadIdx.x;
    int v = (tid < nb) ? bsum[tid] : 0;
    int inc = block_scan_inc(v, wsum);
    if (tid < nb) boff[tid] = inc - v;   // exclusive
}

__global__ void k_scan_apply(const int* __restrict__ deg, const int* __restrict__ boff,
                             int* __restrict__ row_ptr, int N) {
    __shared__ int wsum[4];
    int b = blockIdx.x, i = b * 256 + threadIdx.x;
    int v = (i < N) ? deg[i] : 0;
    int inc = block_scan_inc(v, wsum) + boff[b];
    if (i < N) {
        row_ptr[i] = inc - v;
        if (i == N - 1) row_ptr[N] = inc;
    }
}

__global__ void k_scatter(const int* __restrict__ src, const int* __restrict__ dst, int E,
                          const int* __restrict__ row_ptr, int* __restrict__ fill,
                          int* __restrict__ csr_src) {
    int e = blockIdx.x * blockDim.x + threadIdx.x;
    if (e < E) {
        int d = dst[e];
        int pos = row_ptr[d] + atomicAdd(&fill[d], 1);
        csr_src[pos] = src[e];
    }
}

// td2[d] = ( dis[d] * (sum xp[s] + xp[d]),  dis[d] )
__global__ void k_agg_scalar(const float* __restrict__ xp, const float* __restrict__ dis,
                             const int* __restrict__ row_ptr, const int* __restrict__ csr,
                             float2* __restrict__ td2, int N) {
    int d = blockIdx.x * blockDim.x + threadIdx.x;
    if (d >= N) return;
    float acc = xp[d];
    int e0 = row_ptr[d], e1 = row_ptr[d + 1];
    int e = e0;
    for (; e + 8 <= e1; e += 8) {
        int s0 = csr[e],     s1 = csr[e + 1], s2 = csr[e + 2], s3 = csr[e + 3];
        int s4 = csr[e + 4], s5 = csr[e + 5], s6 = csr[e + 6], s7 = csr[e + 7];
        acc += ((xp[s0] + xp[s1]) + (xp[s2] + xp[s3]))
             + ((xp[s4] + xp[s5]) + (xp[s6] + xp[s7]));
    }
    for (; e < e1; ++e) acc += xp[csr[e]];
    float dd = dis[d];
    td2[d] = make_float2(dd * acc, dd);
}

// ---------------------------------------------------------------------------
// Layer 2 fused: gather-RECOMPUTE h1 rows from (t,dis) scalars -> LDS A-tile,
// then tile-GEMM with W2. h1'[s][j] = dis[s]*relu(t[s]*W1[j]+b1[j]);
// Al[d] = dis[d]*(sum_s h1'[s] + h1'[d]);  B2[d] = dis[d]*relu(Al[d]@W2 + b2).
// Gather is VALU-light (12 ops/edge/lane) + 8B L2 loads -> occupancy-tolerant.
__global__ __launch_bounds__(256, 3) void k_fused_l2(
        const float2* __restrict__ td2, const float* __restrict__ dis,
        const float4* __restrict__ W1f4, const float4* __restrict__ b1f4,
        const float* __restrict__ W2, const float* __restrict__ b2,
        const int* __restrict__ row_ptr, const int* __restrict__ csr,
        float* __restrict__ outp, int N) {
    __shared__ float Al[64][132];
    __shared__ float Wl[32][132];
    const int tid = threadIdx.x;
    const int n0 = blockIdx.x * 64;

    // W2 chunk-0 prefetch: completes during gather phase
    float4 wpf[4];
#pragma unroll
    for (int p = 0; p < 4; ++p) {
        int idx = tid + p * 256;
        int kk = idx >> 5, jc = idx & 31;
        wpf[p] = reinterpret_cast<const float4*>(W2 + (size_t)kk * 128)[jc];
    }

    // ---- phase 1: recompute-gather into Al ----
    {
        const int sub = tid >> 5, lane = tid & 31;
        const float4 w1 = W1f4[lane];    // W1[lane*4 .. +3]
        const float4 bv = b1f4[lane];
        for (int r = 0; r < 8; ++r) {
            int nn = r * 8 + sub;
            int node = n0 + nn;
            float a0 = 0.f, a1 = 0.f, a2 = 0.f, a3 = 0.f;
            if (node < N) {
                float2 sv = td2[node];
                float dd = sv.y;
                a0 = dd * fmaxf(fmaf(sv.x, w1.x, bv.x), 0.f);
                a1 = dd * fmaxf(fmaf(sv.x, w1.y, bv.y), 0.f);
                a2 = dd * fmaxf(fmaf(sv.x, w1.z, bv.z), 0.f);
                a3 = dd * fmaxf(fmaf(sv.x, w1.w, bv.w), 0.f);
                int e0 = row_ptr[node], e1 = row_ptr[node + 1];
                int e = e0;
                for (; e + 4 <= e1; e += 4) {
                    int s0 = csr[e], s1 = csr[e + 1], s2 = csr[e + 2], s3 = csr[e + 3];
                    float2 v0 = td2[s0], v1 = td2[s1], v2 = td2[s2], v3 = td2[s3];
                    a0 += (v0.y * fmaxf(fmaf(v0.x, w1.x, bv.x), 0.f)
                         + v1.y * fmaxf(fmaf(v1.x, w1.x, bv.x), 0.f))
                        + (v2.y * fmaxf(fmaf(v2.x, w1.x, bv.x), 0.f)
                         + v3.y * fmaxf(fmaf(v3.x, w1.x, bv.x), 0.f));
                    a1 += (v0.y * fmaxf(fmaf(v0.x, w1.y, bv.y), 0.f)
                         + v1.y * fmaxf(fmaf(v1.x, w1.y, bv.y), 0.f))
                        + (v2.y * fmaxf(fmaf(v2.x, w1.y, bv.y), 0.f)
                         + v3.y * fmaxf(fmaf(v3.x, w1.y, bv.y), 0.f));
                    a2 += (v0.y * fmaxf(fmaf(v0.x, w1.z, bv.z), 0.f)
                         + v1.y * fmaxf(fmaf(v1.x, w1.z, bv.z), 0.f))
                        + (v2.y * fmaxf(fmaf(v2.x, w1.z, bv.z), 0.f)
                         + v3.y * fmaxf(fmaf(v3.x, w1.z, bv.z), 0.f));
                    a3 += (v0.y * fmaxf(fmaf(v0.x, w1.w, bv.w), 0.f)
                         + v1.y * fmaxf(fmaf(v1.x, w1.w, bv.w), 0.f))
                        + (v2.y * fmaxf(fmaf(v2.x, w1.w, bv.w), 0.f)
                         + v3.y * fmaxf(fmaf(v3.x, w1.w, bv.w), 0.f));
                }
                for (; e < e1; ++e) {
                    float2 v = td2[csr[e]];
                    float rl;
                    rl = fmaxf(fmaf(v.x, w1.x, bv.x), 0.f); a0 += v.y * rl;
                    rl = fmaxf(fmaf(v.x, w1.y, bv.y), 0.f); a1 += v.y * rl;
                    rl = fmaxf(fmaf(v.x, w1.z, bv.z), 0.f); a2 += v.y * rl;
                    rl = fmaxf(fmaf(v.x, w1.w, bv.w), 0.f); a3 += v.y * rl;
                }
                a0 *= dd; a1 *= dd; a2 *= dd; a3 *= dd;
            }
            *reinterpret_cast<float4*>(&Al[nn][lane * 4]) = make_float4(a0, a1, a2, a3);
        }
    }
    __syncthreads();

    // ---- phase 2: GEMM from LDS (W2, FOUT=128) ----
    const int ng = tid >> 4;
    const int cg = tid & 15;
    float acc[4][8] = {};

    for (int kc = 0; kc < 128; kc += 32) {
#pragma unroll
        for (int p = 0; p < 4; ++p) {
            int idx = tid + p * 256;
            int kk = idx >> 5, jc = idx & 31;
            *reinterpret_cast<float4*>(&Wl[kk][jc * 4]) = wpf[p];
        }
        __syncthreads();
        if (kc + 32 < 128) {
#pragma unroll
            for (int p = 0; p < 4; ++p) {
                int idx = tid + p * 256;
                int kk = idx >> 5, jc = idx & 31;
                wpf[p] = reinterpret_cast<const float4*>(
                    W2 + (size_t)(kc + 32 + kk) * 128)[jc];
            }
        }
#pragma unroll
        for (int k4 = 0; k4 < 8; ++k4) {
            float4 A0 = *reinterpret_cast<const float4*>(&Al[ng     ][kc + k4 * 4]);
            float4 A1 = *reinterpret_cast<const float4*>(&Al[ng + 16][kc + k4 * 4]);
            float4 A2 = *reinterpret_cast<const float4*>(&Al[ng + 32][kc + k4 * 4]);
            float4 A3 = *reinterpret_cast<const float4*>(&Al[ng + 48][kc + k4 * 4]);
            const float am[4][4] = {{A0.x,A0.y,A0.z,A0.w},{A1.x,A1.y,A1.z,A1.w},
                                    {A2.x,A2.y,A2.z,A2.w},{A3.x,A3.y,A3.z,A3.w}};
#pragma unroll
            for (int kk = 0; kk < 4; ++kk) {
                float4 w0 = *reinterpret_cast<const float4*>(&Wl[k4 * 4 + kk][cg * 4]);
                float4 w1 = *reinterpret_cast<const float4*>(&Wl[k4 * 4 + kk][64 + cg * 4]);
                const float wv[8] = {w0.x,w0.y,w0.z,w0.w,w1.x,w1.y,w1.z,w1.w};
#pragma unroll
                for (int m = 0; m < 4; ++m)
#pragma unroll
                    for (int j = 0; j < 8; ++j)
                        acc[m][j] = fmaf(am[m][kk], wv[j], acc[m][j]);
            }
        }
        __syncthreads();
    }

    float bb[8];
#pragma unroll
    for (int s = 0; s < 2; ++s)
#pragma unroll
        for (int r = 0; r < 4; ++r)
            bb[s * 4 + r] = b2[cg * 4 + 64 * s + r];

#pragma unroll
    for (int m = 0; m < 4; ++m) {
        int node = n0 + ng + 16 * m;
        if (node < N) {
            float dsc = dis[node];
            float* op = outp + (size_t)node * 128;
#pragma unroll
            for (int s = 0; s < 2; ++s) {
                float o[4];
#pragma unroll
                for (int r = 0; r < 4; ++r)
                    o[r] = fmaxf(acc[m][s * 4 + r] + bb[s * 4 + r], 0.f) * dsc;
                *reinterpret_cast<float4*>(op + cg * 4 + 64 * s) =
                    make_float4(o[0], o[1], o[2], o[3]);
            }
        }
    }
}

// out[d][:] = dis[d] * ( sum_{s in N(d)} hp[s][:] + hp[d][:] ),  F = 128
// LDS-free, high-occupancy, 8-edge unroll. (layer-3 aggregation)
__global__ void k_agg128(const float4* __restrict__ hp4, const float* __restrict__ dis,
                         const int* __restrict__ row_ptr, const int* __restrict__ csr,
                         float4* __restrict__ out4, int N) {
    int node = blockIdx.x * 8 + (threadIdx.x >> 5);
    int lane = threadIdx.x & 31;
    if (node >= N) return;
    float4 self = hp4[(size_t)node * 32 + lane];
    float a0 = self.x, a1 = self.y, a2 = self.z, a3 = self.w;
    int e0 = row_ptr[node], e1 = row_ptr[node + 1];
    int e = e0;
    for (; e + 8 <= e1; e += 8) {
        int s0 = csr[e],     s1 = csr[e + 1], s2 = csr[e + 2], s3 = csr[e + 3];
        int s4 = csr[e + 4], s5 = csr[e + 5], s6 = csr[e + 6], s7 = csr[e + 7];
        float4 v0 = hp4[(size_t)s0 * 32 + lane];
        float4 v1 = hp4[(size_t)s1 * 32 + lane];
        float4 v2 = hp4[(size_t)s2 * 32 + lane];
        float4 v3 = hp4[(size_t)s3 * 32 + lane];
        float4 v4 = hp4[(size_t)s4 * 32 + lane];
        float4 v5 = hp4[(size_t)s5 * 32 + lane];
        float4 v6 = hp4[(size_t)s6 * 32 + lane];
        float4 v7 = hp4[(size_t)s7 * 32 + lane];
        a0 += ((v0.x + v1.x) + (v2.x + v3.x)) + ((v4.x + v5.x) + (v6.x + v7.x));
        a1 += ((v0.y + v1.y) + (v2.y + v3.y)) + ((v4.y + v5.y) + (v6.y + v7.y));
        a2 += ((v0.z + v1.z) + (v2.z + v3.z)) + ((v4.z + v5.z) + (v6.z + v7.z));
        a3 += ((v0.w + v1.w) + (v2.w + v3.w)) + ((v4.w + v5.w) + (v6.w + v7.w));
    }
    for (; e < e1; ++e) {
        int s = csr[e];
        float4 v = hp4[(size_t)s * 32 + lane];
        a0 += v.x; a1 += v.y; a2 += v.z; a3 += v.w;
    }
    float d = dis[node];
    out4[(size_t)node * 32 + lane] = make_float4(a0 * d, a1 * d, a2 * d, a3 * d);
}

// Layer-3 GEMM (R2 geometry, 26KB LDS) + fused per-graph max-pool epilogue.
// relu(A@W3 + b3) -> per-graph max -> shfl-reduce over node lanes -> atomicMax.
__global__ __launch_bounds__(256, 4) void k_gemm3(
        const float* __restrict__ A, const float* __restrict__ W,
        const float* __restrict__ b, const int* __restrict__ batch,
        unsigned int* __restrict__ gmax, int N) {
    __shared__ float Al[64][36];
    __shared__ float Wl[32][132];
    const int tid = threadIdx.x;
    const int n0 = blockIdx.x * 64;
    const int jh = blockIdx.y;
    const int ng = tid >> 4;
    const int cg = tid & 15;

    float acc[4][8] = {};

    for (int kc = 0; kc < 128; kc += 32) {
        for (int idx = tid; idx < 512; idx += 256) {
            int nn = idx >> 3, kq = idx & 7;
            int node = n0 + nn;
            float4 a = (node < N)
                ? reinterpret_cast<const float4*>(A + (size_t)node * 128 + kc)[kq]
                : make_float4(0.f, 0.f, 0.f, 0.f);
            *reinterpret_cast<float4*>(&Al[nn][kq * 4]) = a;
        }
        for (int idx = tid; idx < 1024; idx += 256) {
            int kk = idx >> 5, jc = idx & 31;
            float4 w = reinterpret_cast<const float4*>(
                W + (size_t)(kc + kk) * 256 + jh * 128)[jc];
            *reinterpret_cast<float4*>(&Wl[kk][jc * 4]) = w;
        }
        __syncthreads();

#pragma unroll
        for (int k4 = 0; k4 < 8; ++k4) {
            float4 a0 = *reinterpret_cast<const float4*>(&Al[ng     ][k4 * 4]);
            float4 a1 = *reinterpret_cast<const float4*>(&Al[ng + 16][k4 * 4]);
            float4 a2 = *reinterpret_cast<const float4*>(&Al[ng + 32][k4 * 4]);
            float4 a3 = *reinterpret_cast<const float4*>(&Al[ng + 48][k4 * 4]);
            const float am[4][4] = {{a0.x,a0.y,a0.z,a0.w},{a1.x,a1.y,a1.z,a1.w},
                                    {a2.x,a2.y,a2.z,a2.w},{a3.x,a3.y,a3.z,a3.w}};
#pragma unroll
            for (int kk = 0; kk < 4; ++kk) {
                float4 w0 = *reinterpret_cast<const float4*>(&Wl[k4 * 4 + kk][cg * 4]);
                float4 w1 = *reinterpret_cast<const float4*>(&Wl[k4 * 4 + kk][64 + cg * 4]);
                const float wv[8] = {w0.x,w0.y,w0.z,w0.w,w1.x,w1.y,w1.z,w1.w};
#pragma unroll
                for (int m = 0; m < 4; ++m)
#pragma unroll
                    for (int j = 0; j < 8; ++j)
                        acc[m][j] = fmaf(am[m][kk], wv[j], acc[m][j]);
            }
        }
        __syncthreads();
    }

    // relu(+bias) in registers
#pragma unroll
    for (int s = 0; s < 2; ++s)
#pragma unroll
        for (int r = 0; r < 4; ++r) {
            float bv = b[jh * 128 + cg * 4 + 64 * s + r];
#pragma unroll
            for (int m = 0; m < 4; ++m)
                acc[m][s * 4 + r] = fmaxf(acc[m][s * 4 + r] + bv, 0.f);
        }

    int nbm[4];
#pragma unroll
    for (int m = 0; m < 4; ++m) {
        int node = n0 + ng + 16 * m;
        nbm[m] = (node < N) ? batch[node] : -1;
    }
    int gfirst = batch[n0];
    int glast  = batch[min(n0 + 63, N - 1)];
    for (int gb = gfirst; gb <= glast; ++gb) {
        float mx[8];
#pragma unroll
        for (int j = 0; j < 8; ++j) mx[j] = 0.f;
#pragma unroll
        for (int m = 0; m < 4; ++m)
            if (nbm[m] == gb)
#pragma unroll
                for (int j = 0; j < 8; ++j) mx[j] = fmaxf(mx[j], acc[m][j]);
        // reduce over ng within the wave (lane bits 4,5)
#pragma unroll
        for (int j = 0; j < 8; ++j) {
            mx[j] = fmaxf(mx[j], __shfl_xor(mx[j], 16));
            mx[j] = fmaxf(mx[j], __shfl_xor(mx[j], 32));
        }
        if ((tid & 48) == 0) {
#pragma unroll
            for (int s = 0; s < 2; ++s)
#pragma unroll
                for (int r = 0; r < 4; ++r)
                    atomicMax(&gmax[gb * 256 + jh * 128 + cg * 4 + 64 * s + r],
                              __float_as_uint(mx[s * 4 + r]));
        }
    }
}

// final MLP: out = relu( relu(g@Wf1+bf1) @ Wf2 + bf2 )
__global__ void k_mlp(const float* __restrict__ g, const float* __restrict__ Wf1,
                      const float* __restrict__ bf1, const float* __restrict__ Wf2,
                      const float* __restrict__ bf2, float* __restrict__ out) {
    __shared__ float gr[256];
    __shared__ float g1s[128];
    const int gid = blockIdx.x;
    const int tid = threadIdx.x;
    gr[tid] = g[gid * 256 + tid];
    gr[tid + 128] = g[gid * 256 + 128 + tid];
    __syncthreads();
    float acc = bf1[tid];
    for (int k = 0; k < 256; ++k)
        acc = fmaf(gr[k], Wf1[k * 128 + tid], acc);
    g1s[tid] = fmaxf(acc, 0.f);
    __syncthreads();
    if (tid < 10) {
        float a = bf2[tid];
        for (int k = 0; k < 128; ++k)
            a = fmaf(g1s[k], Wf2[k * 10 + tid], a);
        out[gid * 10 + tid] = fmaxf(a, 0.f);
    }
}

// ---------------------------------------------------------------------------
extern "C" void kernel_launch(void* const* d_in, const int* in_sizes, int n_in,
                              void* d_out, int out_size, void* d_ws, size_t ws_size,
                              hipStream_t stream) {
    const float* x   = (const float*)d_in[0];
    const int*   ei  = (const int*)d_in[1];
    const int*   bat = (const int*)d_in[2];
    const float* W1  = (const float*)d_in[3];
    const float* b1  = (const float*)d_in[4];
    const float* W2  = (const float*)d_in[5];
    const float* b2  = (const float*)d_in[6];
    const float* W3  = (const float*)d_in[7];
    const float* b3  = (const float*)d_in[8];
    const float* Wf1 = (const float*)d_in[9];
    const float* bf1 = (const float*)d_in[10];
    const float* Wf2 = (const float*)d_in[11];
    const float* bf2 = (const float*)d_in[12];
    float* out = (float*)d_out;

    const int N = in_sizes[0];          // 50000
    const int E = in_sizes[1] / 2;      // 800000
    const int* src = ei;
    const int* dst = ei + E;

    char* base = (char*)d_ws;
    size_t off = 0;
    auto carve = [&](size_t bytes) -> char* {
        char* p = base + off;
        off = (off + bytes + 255) & ~(size_t)255;
        return p;
    };
    const int nb = (N + 255) / 256;
    int*    deg     = (int*)   carve((size_t)N * 4);
    int*    fill    = (int*)   carve((size_t)N * 4);
    int*    row_ptr = (int*)   carve((size_t)(N + 1) * 4);
    int*    csr     = (int*)   carve((size_t)E * 4);
    float*  dis     = (float*) carve((size_t)N * 4);
    float*  xp      = (float*) carve((size_t)N * 4);
    float2* td2     = (float2*)carve((size_t)N * 8);
    float*  B2      = (float*) carve((size_t)N * 128 * 4);
    float*  A3      = (float*) carve((size_t)N * 128 * 4);
    unsigned int* g = (unsigned int*)carve((size_t)N_GRAPHS * 256 * 4);
    int*    bsum    = (int*)   carve((size_t)nb * 4);
    int*    boff    = (int*)   carve((size_t)nb * 4);
    (void)ws_size; (void)n_in; (void)out_size;

    hipMemsetAsync(deg, 0, (size_t)N * 4, stream);
    hipMemsetAsync(fill, 0, (size_t)N * 4, stream);
    hipMemsetAsync(g, 0, (size_t)N_GRAPHS * 256 * 4, stream);

    int eb = (E + 255) / 256;

    k_deg<<<eb, 256, 0, stream>>>(dst, E, deg);
    k_dis_bsum<<<nb, 256, 0, stream>>>(deg, x, dis, xp, bsum, N);
    k_scan_sums<<<1, 256, 0, stream>>>(bsum, nb, boff);
    k_scan_apply<<<nb, 256, 0, stream>>>(deg, boff, row_ptr, N);
    k_scatter<<<eb, 256, 0, stream>>>(src, dst, E, row_ptr, fill, csr);

    k_agg_scalar<<<nb, 256, 0, stream>>>(xp, dis, row_ptr, csr, td2, N);

    const int gx = (N + 63) / 64;
    // layer 1+2 fused: recompute-gather h1 from (t,dis) + GEMM W2 -> B2
    k_fused_l2<<<gx, 256, 0, stream>>>(
        td2, dis, (const float4*)W1, (const float4*)b1, W2, b2,
        row_ptr, csr, B2, N);

    // layer 3: row-gather aggregation, then GEMM W3 + fused max-pool
    k_agg128<<<(N + 7) / 8, 256, 0, stream>>>((const float4*)B2, dis, row_ptr, csr,
                                              (float4*)A3, N);
    k_gemm3<<<dim3(gx, 2), 256, 0, stream>>>(A3, W3, b3, bat, g, N);

    k_mlp<<<N_GRAPHS, 128, 0, stream>>>((const float*)g, Wf1, bf1, Wf2, bf2, out);
}

// Round 7
// 286.066 us; speedup vs baseline: 1.4294x; 1.1492x over previous
//
#include <hip/hip_runtime.h>
#include <hip/hip_bf16.h>

#define N_GRAPHS 64

// ---------------------------------------------------------------------------
__global__ void k_deg(const int* __restrict__ dst, int E, int* __restrict__ deg) {
    int i = blockIdx.x * blockDim.x + threadIdx.x;
    if (i < E) atomicAdd(&deg[dst[i]], 1);
}

// dis/xp + per-block deg sums (fused)
__global__ void k_dis_bsum(const int* __restrict__ deg, const float* __restrict__ x,
                           float* __restrict__ dis, float* __restrict__ xp,
                           int* __restrict__ bsum, int N) {
    int i = blockIdx.x * 256 + threadIdx.x;
    int dv = (i < N) ? deg[i] : 0;
    if (i < N) {
        float d = rsqrtf((float)(dv + 1));
        dis[i] = d;
        xp[i]  = d * x[i];
    }
    int v = dv;
#pragma unroll
    for (int o = 1; o < 64; o <<= 1) v += __shfl_xor(v, o);
    __shared__ int ws4[4];
    if ((threadIdx.x & 63) == 0) ws4[threadIdx.x >> 6] = v;
    __syncthreads();
    if (threadIdx.x == 0) bsum[blockIdx.x] = ws4[0] + ws4[1] + ws4[2] + ws4[3];
}

__device__ inline int block_scan_inc(int v, int* wsum) {
    int lane = threadIdx.x & 63, w = threadIdx.x >> 6;
    int iv = v;
#pragma unroll
    for (int o = 1; o < 64; o <<= 1) {
        int t = __shfl_up(iv, o);
        if (lane >= o) iv += t;
    }
    if (lane == 63) wsum[w] = iv;
    __syncthreads();
    int add = 0;
    for (int k = 0; k < w; ++k) add += wsum[k];
    return iv + add;
}

__global__ void k_scan_sums(const int* __restrict__ bsum, int nb, int* __restrict__ boff) {
    __shared__ int wsum[4];
    int tid = threadIdx.x;
    int v = (tid < nb) ? bsum[tid] : 0;
    int inc = block_scan_inc(v, wsum);
    if (tid < nb) boff[tid] = inc - v;   // exclusive
}

__global__ void k_scan_apply(const int* __restrict__ deg, const int* __restrict__ boff,
                             int* __restrict__ row_ptr, int N) {
    __shared__ int wsum[4];
    int b = blockIdx.x, i = b * 256 + threadIdx.x;
    int v = (i < N) ? deg[i] : 0;
    int inc = block_scan_inc(v, wsum) + boff[b];
    if (i < N) {
        row_ptr[i] = inc - v;
        if (i == N - 1) row_ptr[N] = inc;
    }
}

__global__ void k_scatter(const int* __restrict__ src, const int* __restrict__ dst, int E,
                          const int* __restrict__ row_ptr, int* __restrict__ fill,
                          int* __restrict__ csr_src) {
    int e = blockIdx.x * blockDim.x + threadIdx.x;
    if (e < E) {
        int d = dst[e];
        int pos = row_ptr[d] + atomicAdd(&fill[d], 1);
        csr_src[pos] = src[e];
    }
}

// td2[d] = ( dis[d] * (sum xp[s] + xp[d]),  dis[d] )
__global__ void k_agg_scalar(const float* __restrict__ xp, const float* __restrict__ dis,
                             const int* __restrict__ row_ptr, const int* __restrict__ csr,
                             float2* __restrict__ td2, int N) {
    int d = blockIdx.x * blockDim.x + threadIdx.x;
    if (d >= N) return;
    float acc = xp[d];
    int e0 = row_ptr[d], e1 = row_ptr[d + 1];
    int e = e0;
    for (; e + 8 <= e1; e += 8) {
        int s0 = csr[e],     s1 = csr[e + 1], s2 = csr[e + 2], s3 = csr[e + 3];
        int s4 = csr[e + 4], s5 = csr[e + 5], s6 = csr[e + 6], s7 = csr[e + 7];
        acc += ((xp[s0] + xp[s1]) + (xp[s2] + xp[s3]))
             + ((xp[s4] + xp[s5]) + (xp[s6] + xp[s7]));
    }
    for (; e < e1; ++e) acc += xp[csr[e]];
    float dd = dis[d];
    td2[d] = make_float2(dd * acc, dd);
}

// ---------------------------------------------------------------------------
// Layer-2 aggregation with rank-1 h1 recompute (LDS-free, high occupancy):
//   h1'[s][j] = dis[s]*relu(t[s]*W1[j]+b1[j])   (from 8B td2[s] = (t,dis))
//   A2[d][:]  = dis[d]*( sum_{s in N(d)} h1'[s] + h1'[d] )
// 32 lanes/node (4 features each), 8 nodes/block, 8-edge unroll.
__global__ void k_h1agg(const float2* __restrict__ td2,
                        const float4* __restrict__ W1f4, const float4* __restrict__ b1f4,
                        const int* __restrict__ row_ptr, const int* __restrict__ csr,
                        float4* __restrict__ out4, int N) {
    int node = blockIdx.x * 8 + (threadIdx.x >> 5);
    int lane = threadIdx.x & 31;
    if (node >= N) return;
    const float4 w1 = W1f4[lane];
    const float4 bv = b1f4[lane];
    float2 sv = td2[node];
    float dd = sv.y;
    float a0 = dd * fmaxf(fmaf(sv.x, w1.x, bv.x), 0.f);
    float a1 = dd * fmaxf(fmaf(sv.x, w1.y, bv.y), 0.f);
    float a2 = dd * fmaxf(fmaf(sv.x, w1.z, bv.z), 0.f);
    float a3 = dd * fmaxf(fmaf(sv.x, w1.w, bv.w), 0.f);
    int e0 = row_ptr[node], e1 = row_ptr[node + 1];
    int e = e0;
    for (; e + 8 <= e1; e += 8) {
        int s0 = csr[e],     s1 = csr[e + 1], s2 = csr[e + 2], s3 = csr[e + 3];
        int s4 = csr[e + 4], s5 = csr[e + 5], s6 = csr[e + 6], s7 = csr[e + 7];
        float2 v0 = td2[s0], v1 = td2[s1], v2 = td2[s2], v3 = td2[s3];
        float2 v4 = td2[s4], v5 = td2[s5], v6 = td2[s6], v7 = td2[s7];
        a0 += ((v0.y * fmaxf(fmaf(v0.x, w1.x, bv.x), 0.f)
              + v1.y * fmaxf(fmaf(v1.x, w1.x, bv.x), 0.f))
             + (v2.y * fmaxf(fmaf(v2.x, w1.x, bv.x), 0.f)
              + v3.y * fmaxf(fmaf(v3.x, w1.x, bv.x), 0.f)))
            + ((v4.y * fmaxf(fmaf(v4.x, w1.x, bv.x), 0.f)
              + v5.y * fmaxf(fmaf(v5.x, w1.x, bv.x), 0.f))
             + (v6.y * fmaxf(fmaf(v6.x, w1.x, bv.x), 0.f)
              + v7.y * fmaxf(fmaf(v7.x, w1.x, bv.x), 0.f)));
        a1 += ((v0.y * fmaxf(fmaf(v0.x, w1.y, bv.y), 0.f)
              + v1.y * fmaxf(fmaf(v1.x, w1.y, bv.y), 0.f))
             + (v2.y * fmaxf(fmaf(v2.x, w1.y, bv.y), 0.f)
              + v3.y * fmaxf(fmaf(v3.x, w1.y, bv.y), 0.f)))
            + ((v4.y * fmaxf(fmaf(v4.x, w1.y, bv.y), 0.f)
              + v5.y * fmaxf(fmaf(v5.x, w1.y, bv.y), 0.f))
             + (v6.y * fmaxf(fmaf(v6.x, w1.y, bv.y), 0.f)
              + v7.y * fmaxf(fmaf(v7.x, w1.y, bv.y), 0.f)));
        a2 += ((v0.y * fmaxf(fmaf(v0.x, w1.z, bv.z), 0.f)
              + v1.y * fmaxf(fmaf(v1.x, w1.z, bv.z), 0.f))
             + (v2.y * fmaxf(fmaf(v2.x, w1.z, bv.z), 0.f)
              + v3.y * fmaxf(fmaf(v3.x, w1.z, bv.z), 0.f)))
            + ((v4.y * fmaxf(fmaf(v4.x, w1.z, bv.z), 0.f)
              + v5.y * fmaxf(fmaf(v5.x, w1.z, bv.z), 0.f))
             + (v6.y * fmaxf(fmaf(v6.x, w1.z, bv.z), 0.f)
              + v7.y * fmaxf(fmaf(v7.x, w1.z, bv.z), 0.f)));
        a3 += ((v0.y * fmaxf(fmaf(v0.x, w1.w, bv.w), 0.f)
              + v1.y * fmaxf(fmaf(v1.x, w1.w, bv.w), 0.f))
             + (v2.y * fmaxf(fmaf(v2.x, w1.w, bv.w), 0.f)
              + v3.y * fmaxf(fmaf(v3.x, w1.w, bv.w), 0.f)))
            + ((v4.y * fmaxf(fmaf(v4.x, w1.w, bv.w), 0.f)
              + v5.y * fmaxf(fmaf(v5.x, w1.w, bv.w), 0.f))
             + (v6.y * fmaxf(fmaf(v6.x, w1.w, bv.w), 0.f)
              + v7.y * fmaxf(fmaf(v7.x, w1.w, bv.w), 0.f)));
    }
    for (; e < e1; ++e) {
        float2 v = td2[csr[e]];
        a0 += v.y * fmaxf(fmaf(v.x, w1.x, bv.x), 0.f);
        a1 += v.y * fmaxf(fmaf(v.x, w1.y, bv.y), 0.f);
        a2 += v.y * fmaxf(fmaf(v.x, w1.z, bv.z), 0.f);
        a3 += v.y * fmaxf(fmaf(v.x, w1.w, bv.w), 0.f);
    }
    out4[(size_t)node * 32 + lane] = make_float4(a0 * dd, a1 * dd, a2 * dd, a3 * dd);
}

// out[d][:] = dis[d] * ( sum_{s in N(d)} hp[s][:] + hp[d][:] ),  F = 128
// LDS-free, high-occupancy, 8-edge unroll. (layer-3 aggregation)
__global__ void k_agg128(const float4* __restrict__ hp4, const float* __restrict__ dis,
                         const int* __restrict__ row_ptr, const int* __restrict__ csr,
                         float4* __restrict__ out4, int N) {
    int node = blockIdx.x * 8 + (threadIdx.x >> 5);
    int lane = threadIdx.x & 31;
    if (node >= N) return;
    float4 self = hp4[(size_t)node * 32 + lane];
    float a0 = self.x, a1 = self.y, a2 = self.z, a3 = self.w;
    int e0 = row_ptr[node], e1 = row_ptr[node + 1];
    int e = e0;
    for (; e + 8 <= e1; e += 8) {
        int s0 = csr[e],     s1 = csr[e + 1], s2 = csr[e + 2], s3 = csr[e + 3];
        int s4 = csr[e + 4], s5 = csr[e + 5], s6 = csr[e + 6], s7 = csr[e + 7];
        float4 v0 = hp4[(size_t)s0 * 32 + lane];
        float4 v1 = hp4[(size_t)s1 * 32 + lane];
        float4 v2 = hp4[(size_t)s2 * 32 + lane];
        float4 v3 = hp4[(size_t)s3 * 32 + lane];
        float4 v4 = hp4[(size_t)s4 * 32 + lane];
        float4 v5 = hp4[(size_t)s5 * 32 + lane];
        float4 v6 = hp4[(size_t)s6 * 32 + lane];
        float4 v7 = hp4[(size_t)s7 * 32 + lane];
        a0 += ((v0.x + v1.x) + (v2.x + v3.x)) + ((v4.x + v5.x) + (v6.x + v7.x));
        a1 += ((v0.y + v1.y) + (v2.y + v3.y)) + ((v4.y + v5.y) + (v6.y + v7.y));
        a2 += ((v0.z + v1.z) + (v2.z + v3.z)) + ((v4.z + v5.z) + (v6.z + v7.z));
        a3 += ((v0.w + v1.w) + (v2.w + v3.w)) + ((v4.w + v5.w) + (v6.w + v7.w));
    }
    for (; e < e1; ++e) {
        int s = csr[e];
        float4 v = hp4[(size_t)s * 32 + lane];
        a0 += v.x; a1 += v.y; a2 += v.z; a3 += v.w;
    }
    float d = dis[node];
    out4[(size_t)node * 32 + lane] = make_float4(a0 * d, a1 * d, a2 * d, a3 * d);
}

// GEMM, R2 geometry (26KB LDS, 4 blocks/CU): tile 64 nodes x 128 cols (jh),
// thread tile 4n x 8c split-column. FUSE_MAX: per-graph max-pool epilogue.
template<int FOUT, bool SCALE, bool FUSE_MAX>
__global__ __launch_bounds__(256, 4) void k_gemm(
        const float* __restrict__ A, const float* __restrict__ W,
        const float* __restrict__ b, const float* __restrict__ dis,
        float* __restrict__ outp, const int* __restrict__ batch,
        unsigned int* __restrict__ gmax, int N) {
    __shared__ float Al[64][36];
    __shared__ float Wl[32][132];
    const int tid = threadIdx.x;
    const int n0 = blockIdx.x * 64;
    const int jh = blockIdx.y;
    const int ng = tid >> 4;
    const int cg = tid & 15;

    float acc[4][8] = {};

    for (int kc = 0; kc < 128; kc += 32) {
        for (int idx = tid; idx < 512; idx += 256) {
            int nn = idx >> 3, kq = idx & 7;
            int node = n0 + nn;
            float4 a = (node < N)
                ? reinterpret_cast<const float4*>(A + (size_t)node * 128 + kc)[kq]
                : make_float4(0.f, 0.f, 0.f, 0.f);
            *reinterpret_cast<float4*>(&Al[nn][kq * 4]) = a;
        }
        for (int idx = tid; idx < 1024; idx += 256) {
            int kk = idx >> 5, jc = idx & 31;
            float4 w = reinterpret_cast<const float4*>(
                W + (size_t)(kc + kk) * FOUT + jh * 128)[jc];
            *reinterpret_cast<float4*>(&Wl[kk][jc * 4]) = w;
        }
        __syncthreads();

#pragma unroll
        for (int k4 = 0; k4 < 8; ++k4) {
            float4 a0 = *reinterpret_cast<const float4*>(&Al[ng     ][k4 * 4]);
            float4 a1 = *reinterpret_cast<const float4*>(&Al[ng + 16][k4 * 4]);
            float4 a2 = *reinterpret_cast<const float4*>(&Al[ng + 32][k4 * 4]);
            float4 a3 = *reinterpret_cast<const float4*>(&Al[ng + 48][k4 * 4]);
            const float am[4][4] = {{a0.x,a0.y,a0.z,a0.w},{a1.x,a1.y,a1.z,a1.w},
                                    {a2.x,a2.y,a2.z,a2.w},{a3.x,a3.y,a3.z,a3.w}};
#pragma unroll
            for (int kk = 0; kk < 4; ++kk) {
                float4 w0 = *reinterpret_cast<const float4*>(&Wl[k4 * 4 + kk][cg * 4]);
                float4 w1 = *reinterpret_cast<const float4*>(&Wl[k4 * 4 + kk][64 + cg * 4]);
                const float wv[8] = {w0.x,w0.y,w0.z,w0.w,w1.x,w1.y,w1.z,w1.w};
#pragma unroll
                for (int m = 0; m < 4; ++m)
#pragma unroll
                    for (int j = 0; j < 8; ++j)
                        acc[m][j] = fmaf(am[m][kk], wv[j], acc[m][j]);
            }
        }
        __syncthreads();
    }

    if (!FUSE_MAX) {
        float bb[8];
#pragma unroll
        for (int s = 0; s < 2; ++s)
#pragma unroll
            for (int r = 0; r < 4; ++r)
                bb[s * 4 + r] = b[jh * 128 + cg * 4 + 64 * s + r];
#pragma unroll
        for (int m = 0; m < 4; ++m) {
            int node = n0 + ng + 16 * m;
            if (node < N) {
                float dsc = SCALE ? dis[node] : 1.f;
                float* op = outp + (size_t)node * FOUT + jh * 128;
#pragma unroll
                for (int s = 0; s < 2; ++s) {
                    float o[4];
#pragma unroll
                    for (int r = 0; r < 4; ++r) {
                        float v = fmaxf(acc[m][s * 4 + r] + bb[s * 4 + r], 0.f);
                        o[r] = SCALE ? v * dsc : v;
                    }
                    *reinterpret_cast<float4*>(op + cg * 4 + 64 * s) =
                        make_float4(o[0], o[1], o[2], o[3]);
                }
            }
        }
    } else {
        // relu(+bias) in registers, then per-graph max -> atomicMax
#pragma unroll
        for (int s = 0; s < 2; ++s)
#pragma unroll
            for (int r = 0; r < 4; ++r) {
                float bv = b[jh * 128 + cg * 4 + 64 * s + r];
#pragma unroll
                for (int m = 0; m < 4; ++m)
                    acc[m][s * 4 + r] = fmaxf(acc[m][s * 4 + r] + bv, 0.f);
            }
        int nbm[4];
#pragma unroll
        for (int m = 0; m < 4; ++m) {
            int node = n0 + ng + 16 * m;
            nbm[m] = (node < N) ? batch[node] : -1;
        }
        int gfirst = batch[n0];
        int glast  = batch[min(n0 + 63, N - 1)];
        for (int gb = gfirst; gb <= glast; ++gb) {
            float mx[8];
#pragma unroll
            for (int j = 0; j < 8; ++j) mx[j] = 0.f;
#pragma unroll
            for (int m = 0; m < 4; ++m)
                if (nbm[m] == gb)
#pragma unroll
                    for (int j = 0; j < 8; ++j) mx[j] = fmaxf(mx[j], acc[m][j]);
#pragma unroll
            for (int j = 0; j < 8; ++j) {
                mx[j] = fmaxf(mx[j], __shfl_xor(mx[j], 16));
                mx[j] = fmaxf(mx[j], __shfl_xor(mx[j], 32));
            }
            if ((tid & 48) == 0) {
#pragma unroll
                for (int s = 0; s < 2; ++s)
#pragma unroll
                    for (int r = 0; r < 4; ++r)
                        atomicMax(&gmax[gb * 256 + jh * 128 + cg * 4 + 64 * s + r],
                                  __float_as_uint(mx[s * 4 + r]));
            }
        }
    }
}

// final MLP: out = relu( relu(g@Wf1+bf1) @ Wf2 + bf2 )
__global__ void k_mlp(const float* __restrict__ g, const float* __restrict__ Wf1,
                      const float* __restrict__ bf1, const float* __restrict__ Wf2,
                      const float* __restrict__ bf2, float* __restrict__ out) {
    __shared__ float gr[256];
    __shared__ float g1s[128];
    const int gid = blockIdx.x;
    const int tid = threadIdx.x;
    gr[tid] = g[gid * 256 + tid];
    gr[tid + 128] = g[gid * 256 + 128 + tid];
    __syncthreads();
    float acc = bf1[tid];
    for (int k = 0; k < 256; ++k)
        acc = fmaf(gr[k], Wf1[k * 128 + tid], acc);
    g1s[tid] = fmaxf(acc, 0.f);
    __syncthreads();
    if (tid < 10) {
        float a = bf2[tid];
        for (int k = 0; k < 128; ++k)
            a = fmaf(g1s[k], Wf2[k * 10 + tid], a);
        out[gid * 10 + tid] = fmaxf(a, 0.f);
    }
}

// ---------------------------------------------------------------------------
extern "C" void kernel_launch(void* const* d_in, const int* in_sizes, int n_in,
                              void* d_out, int out_size, void* d_ws, size_t ws_size,
                              hipStream_t stream) {
    const float* x   = (const float*)d_in[0];
    const int*   ei  = (const int*)d_in[1];
    const int*   bat = (const int*)d_in[2];
    const float* W1  = (const float*)d_in[3];
    const float* b1  = (const float*)d_in[4];
    const float* W2  = (const float*)d_in[5];
    const float* b2  = (const float*)d_in[6];
    const float* W3  = (const float*)d_in[7];
    const float* b3  = (const float*)d_in[8];
    const float* Wf1 = (const float*)d_in[9];
    const float* bf1 = (const float*)d_in[10];
    const float* Wf2 = (const float*)d_in[11];
    const float* bf2 = (const float*)d_in[12];
    float* out = (float*)d_out;

    const int N = in_sizes[0];          // 50000
    const int E = in_sizes[1] / 2;      // 800000
    const int* src = ei;
    const int* dst = ei + E;

    char* base = (char*)d_ws;
    size_t off = 0;
    auto carve = [&](size_t bytes) -> char* {
        char* p = base + off;
        off = (off + bytes + 255) & ~(size_t)255;
        return p;
    };
    const int nb = (N + 255) / 256;
    int*    deg     = (int*)   carve((size_t)N * 4);
    int*    fill    = (int*)   carve((size_t)N * 4);
    int*    row_ptr = (int*)   carve((size_t)(N + 1) * 4);
    int*    csr     = (int*)   carve((size_t)E * 4);
    float*  dis     = (float*) carve((size_t)N * 4);
    float*  xp      = (float*) carve((size_t)N * 4);
    float2* td2     = (float2*)carve((size_t)N * 8);
    float*  A2      = (float*) carve((size_t)N * 128 * 4);
    float*  B2      = (float*) carve((size_t)N * 128 * 4);
    float*  A3      = (float*) carve((size_t)N * 128 * 4);
    unsigned int* g = (unsigned int*)carve((size_t)N_GRAPHS * 256 * 4);
    int*    bsum    = (int*)   carve((size_t)nb * 4);
    int*    boff    = (int*)   carve((size_t)nb * 4);
    (void)ws_size; (void)n_in; (void)out_size;

    hipMemsetAsync(deg, 0, (size_t)N * 4, stream);
    hipMemsetAsync(fill, 0, (size_t)N * 4, stream);
    hipMemsetAsync(g, 0, (size_t)N_GRAPHS * 256 * 4, stream);

    int eb = (E + 255) / 256;

    k_deg<<<eb, 256, 0, stream>>>(dst, E, deg);
    k_dis_bsum<<<nb, 256, 0, stream>>>(deg, x, dis, xp, bsum, N);
    k_scan_sums<<<1, 256, 0, stream>>>(bsum, nb, boff);
    k_scan_apply<<<nb, 256, 0, stream>>>(deg, boff, row_ptr, N);
    k_scatter<<<eb, 256, 0, stream>>>(src, dst, E, row_ptr, fill, csr);

    k_agg_scalar<<<nb, 256, 0, stream>>>(xp, dis, row_ptr, csr, td2, N);

    const int gx = (N + 63) / 64;
    const int ab = (N + 7) / 8;

    // layer 1+2: recompute-gather h1 -> A2 (LDS-free), then GEMM W2 -> B2
    k_h1agg<<<ab, 256, 0, stream>>>(td2, (const float4*)W1, (const float4*)b1,
                                    row_ptr, csr, (float4*)A2, N);
    k_gemm<128, true, false><<<dim3(gx, 1), 256, 0, stream>>>(
        A2, W2, b2, dis, B2, nullptr, nullptr, N);

    // layer 3: row-gather aggregation, then GEMM W3 + fused max-pool
    k_agg128<<<ab, 256, 0, stream>>>((const float4*)B2, dis, row_ptr, csr,
                                     (float4*)A3, N);
    k_gemm<256, false, true><<<dim3(gx, 2), 256, 0, stream>>>(
        A3, W3, b3, nullptr, nullptr, bat, g, N);

    k_mlp<<<N_GRAPHS, 128, 0, stream>>>((const float*)g, Wf1, bf1, Wf2, bf2, out);
}